// Round 1
// baseline (282.092 us; speedup 1.0000x reference)
//
#include <hip/hip_runtime.h>

#define NTOK 4096   // H*W
#define NB 4

typedef short bf16x8 __attribute__((ext_vector_type(8)));
typedef float f32x4 __attribute__((ext_vector_type(4)));

__device__ __forceinline__ short f2bf(float f) {
  union { float f; unsigned u; } v; v.f = f;
  unsigned r = v.u + 0x7fffu + ((v.u >> 16) & 1u);
  return (short)(r >> 16);
}
__device__ __forceinline__ float bf2f(short s) {
  union { unsigned u; float f; } v; v.u = ((unsigned)(unsigned short)s) << 16;
  return v.f;
}

struct ConvArgs {
  const float* x;
  const float* w[6];
  const float* bias[6];
  short* out[6];
};

// ---- fused 6-way 1x1 conv: y = x @ W + b, outputs bf16 (token-major) ----
__global__ __launch_bounds__(256) void conv_qkv(ConvArgs args) {
  __shared__ short lWt[6][64*72];   // W^T, bf16, stride 72 (bank-friendly)
  __shared__ float lB[6*64];
  const int tid = threadIdx.x;
  const int wave = tid >> 6, lane = tid & 63;
  const int quad = lane >> 4, l16 = lane & 15;

  for (int wi = 0; wi < 6; wi++) {
    const f32x4* wsrc = (const f32x4*)args.w[wi];
    for (int u0 = 0; u0 < 4; u0++) {
      int u = u0 * 256 + tid;           // float4 unit: c = u>>4, d-quad = u&15
      int c = u >> 4, d4 = u & 15;
      f32x4 v = wsrc[u];
      for (int j = 0; j < 4; j++)
        lWt[wi][(d4*4+j)*72 + c] = f2bf(v[j]);
    }
  }
  if (tid < 64)
    for (int wi = 0; wi < 6; wi++) lB[wi*64 + tid] = args.bias[wi][tid];

  // A fragments: x rows (fp32 -> bf16), A[m=l16][k=quad*8+j]
  int row = blockIdx.x * 64 + wave*16 + l16;
  const float* xr = args.x + (size_t)row*64 + quad*8;
  f32x4 x0 = *(const f32x4*)xr;
  f32x4 x1 = *(const f32x4*)(xr+4);
  f32x4 x2 = *(const f32x4*)(xr+32);
  f32x4 x3 = *(const f32x4*)(xr+36);
  bf16x8 a0, a1;
  for (int j=0;j<4;j++){ a0[j]=f2bf(x0[j]); a0[4+j]=f2bf(x1[j]); a1[j]=f2bf(x2[j]); a1[4+j]=f2bf(x3[j]); }
  __syncthreads();

  int orow_base = blockIdx.x*64 + wave*16 + quad*4;
  for (int wi=0; wi<6; wi++) {
    short* outp = args.out[wi];
    for (int dt=0; dt<4; dt++) {
      bf16x8 b0 = *(const bf16x8*)&lWt[wi][(dt*16+l16)*72 + quad*8];
      bf16x8 b1 = *(const bf16x8*)&lWt[wi][(dt*16+l16)*72 + 32 + quad*8];
      f32x4 acc = {0.f,0.f,0.f,0.f};
      acc = __builtin_amdgcn_mfma_f32_16x16x32_bf16(a0, b0, acc, 0,0,0);
      acc = __builtin_amdgcn_mfma_f32_16x16x32_bf16(a1, b1, acc, 0,0,0);
      float bias = lB[wi*64 + dt*16 + l16];
      for (int r=0;r<4;r++)
        outp[(size_t)(orow_base + r)*64 + dt*16 + l16] = f2bf(acc[r] + bias);
    }
  }
}

// ---- flash-style spatial attention: 1 block per (batch, 64-query tile) ----
__global__ __launch_bounds__(256) void attn_spatial(const short* __restrict__ qs,
    const short* __restrict__ ks, const short* __restrict__ vs,
    float* __restrict__ spat) {
  __shared__ short lK[64*72];       // K tile, row-major (keys x channels)
  __shared__ short lVt[64*72];      // V tile transposed (channels x keys)
  __shared__ short lP[4][16*72];    // per-wave P round-trip buffer
  const int tid = threadIdx.x;
  const int wave = tid>>6, lane = tid&63, quad = lane>>4, l16 = lane&15;
  const int batch = blockIdx.y, qtile = blockIdx.x;

  const short* qp = qs + ((size_t)(batch*NTOK + qtile*64 + wave*16 + l16))*64 + quad*8;
  bf16x8 qa0 = *(const bf16x8*)qp;
  bf16x8 qa1 = *(const bf16x8*)(qp + 32);

  f32x4 o[4];
  for (int ct=0;ct<4;ct++) o[ct] = (f32x4){0.f,0.f,0.f,0.f};
  float mi[4] = {-1e30f,-1e30f,-1e30f,-1e30f};
  float li[4] = {0.f,0.f,0.f,0.f};

  const short* kb = ks + (size_t)batch*NTOK*64;
  const short* vb = vs + (size_t)batch*NTOK*64;

  for (int kt=0; kt<64; kt++) {
    __syncthreads();
    for (int u0=0; u0<2; u0++) {
      int u = u0*256 + tid;           // 512 units of 8 bf16
      int row = u>>3, col8 = u&7;
      const short* src = kb + (size_t)(kt*64 + row)*64 + col8*8;
      *(bf16x8*)&lK[row*72 + col8*8] = *(const bf16x8*)src;
      bf16x8 vv = *(const bf16x8*)(vb + (size_t)(kt*64 + row)*64 + col8*8);
      for (int j=0;j<8;j++) lVt[(col8*8+j)*72 + row] = vv[j];
    }
    __syncthreads();

    // S = Q K^T (scaled), 4 n-tiles of 16 keys
    f32x4 s[4];
    for (int nt=0;nt<4;nt++) {
      bf16x8 k0 = *(const bf16x8*)&lK[(nt*16+l16)*72 + quad*8];
      bf16x8 k1 = *(const bf16x8*)&lK[(nt*16+l16)*72 + 32 + quad*8];
      f32x4 z = {0.f,0.f,0.f,0.f};
      z = __builtin_amdgcn_mfma_f32_16x16x32_bf16(qa0, k0, z, 0,0,0);
      z = __builtin_amdgcn_mfma_f32_16x16x32_bf16(qa1, k1, z, 0,0,0);
      s[nt] = z;
    }
    float alpha[4];
    for (int r=0;r<4;r++) {
      float s0 = s[0][r]*0.125f, s1 = s[1][r]*0.125f;
      float s2 = s[2][r]*0.125f, s3 = s[3][r]*0.125f;
      s[0][r]=s0; s[1][r]=s1; s[2][r]=s2; s[3][r]=s3;
      float mx = fmaxf(fmaxf(s0,s1), fmaxf(s2,s3));
      mx = fmaxf(mx, __shfl_xor(mx, 1));
      mx = fmaxf(mx, __shfl_xor(mx, 2));
      mx = fmaxf(mx, __shfl_xor(mx, 4));
      mx = fmaxf(mx, __shfl_xor(mx, 8));
      float mnew = fmaxf(mi[r], mx);
      alpha[r] = exp2f((mi[r]-mnew)*1.44269504f);
      float sum = 0.f;
      for (int nt=0;nt<4;nt++) {
        float p = exp2f((s[nt][r]-mnew)*1.44269504f);
        s[nt][r] = p; sum += p;
      }
      sum += __shfl_xor(sum,1); sum += __shfl_xor(sum,2);
      sum += __shfl_xor(sum,4); sum += __shfl_xor(sum,8);
      li[r] = li[r]*alpha[r] + sum;
      mi[r] = mnew;
    }
    for (int ct=0;ct<4;ct++)
      for (int r=0;r<4;r++) o[ct][r] *= alpha[r];

    // P: C/D layout -> LDS -> A layout (m120-verified transform)
    short* lPw = lP[wave];
    for (int nt=0;nt<4;nt++)
      for (int r=0;r<4;r++)
        lPw[(quad*4+r)*72 + nt*16 + l16] = f2bf(s[nt][r]);
    bf16x8 pa0 = *(const bf16x8*)&lPw[l16*72 + quad*8];
    bf16x8 pa1 = *(const bf16x8*)&lPw[l16*72 + 32 + quad*8];
    for (int ct=0;ct<4;ct++) {
      bf16x8 v0 = *(const bf16x8*)&lVt[(ct*16+l16)*72 + quad*8];
      bf16x8 v1 = *(const bf16x8*)&lVt[(ct*16+l16)*72 + 32 + quad*8];
      o[ct] = __builtin_amdgcn_mfma_f32_16x16x32_bf16(pa0, v0, o[ct], 0,0,0);
      o[ct] = __builtin_amdgcn_mfma_f32_16x16x32_bf16(pa1, v1, o[ct], 0,0,0);
    }
  }
  int rbase = batch*NTOK + qtile*64 + wave*16 + quad*4;
  for (int ct=0;ct<4;ct++)
    for (int r=0;r<4;r++)
      spat[(size_t)(rbase + r)*64 + ct*16 + l16] = o[ct][r] / li[r];
}

// ---- channel attention: G[c][d] = sum_n Qc[c][n] Kc[d][n], K-split MFMA ----
__global__ __launch_bounds__(256) void chan_qk(const short* __restrict__ qc,
    const short* __restrict__ kc, float* __restrict__ G) {
  __shared__ float red[4096];
  const int tid = threadIdx.x;
  const int wave = tid>>6, lane = tid&63, quad = lane>>4, l16 = lane&15;
  const int batch = blockIdx.y, kchunk = blockIdx.x;
  for (int i=tid;i<4096;i+=256) red[i]=0.f;

  const int kbase = kchunk*256 + wave*64;
  const short* qb = qc + (size_t)batch*NTOK*64;
  const short* kb = kc + (size_t)batch*NTOK*64;

  bf16x8 aq[4][2], bk[4][2];
  for (int mt=0;mt<4;mt++)
    for (int kbi=0;kbi<2;kbi++)
      aq[mt][kbi] = *(const bf16x8*)(qb + (size_t)(mt*16+l16)*4096 + kbase + kbi*32 + quad*8);
  for (int nt=0;nt<4;nt++)
    for (int kbi=0;kbi<2;kbi++)
      bk[nt][kbi] = *(const bf16x8*)(kb + (size_t)(nt*16+l16)*4096 + kbase + kbi*32 + quad*8);
  __syncthreads();
  for (int mt=0;mt<4;mt++)
    for (int nt=0;nt<4;nt++) {
      f32x4 acc = {0.f,0.f,0.f,0.f};
      acc = __builtin_amdgcn_mfma_f32_16x16x32_bf16(aq[mt][0], bk[nt][0], acc, 0,0,0);
      acc = __builtin_amdgcn_mfma_f32_16x16x32_bf16(aq[mt][1], bk[nt][1], acc, 0,0,0);
      for (int r=0;r<4;r++)
        atomicAdd(&red[(mt*16+quad*4+r)*64 + nt*16+l16], acc[r]);
    }
  __syncthreads();
  for (int i=tid;i<4096;i+=256)
    atomicAdd(&G[batch*4096 + i], red[i]);
}

__global__ __launch_bounds__(64) void chan_softmax(const float* __restrict__ G,
    float* __restrict__ att) {
  const int batch = blockIdx.x, c = threadIdx.x;
  const float* g = G + batch*4096 + c*64;
  float mx = -1e30f;
  for (int d=0;d<64;d++) mx = fmaxf(mx, g[d]*0.125f);
  float sum = 0.f;
  for (int d=0;d<64;d++) sum += exp2f((g[d]*0.125f - mx)*1.44269504f);
  float inv = 1.f/sum;
  float* o = att + batch*4096 + c*64;
  for (int d=0;d<64;d++) o[d] = exp2f((g[d]*0.125f - mx)*1.44269504f)*inv;
}

// ---- chan[c][n] = sum_d att[c][d] * Vc[d][n] ----
__global__ __launch_bounds__(256) void chan_av(const float* __restrict__ att,
    const short* __restrict__ vc, float* __restrict__ chan) {
  __shared__ float lA[4096];
  const int tid = threadIdx.x;
  const int batch = blockIdx.y, ch = blockIdx.x;
  for (int i=tid;i<4096;i+=256) lA[i] = att[batch*4096+i];
  __syncthreads();
  const int n = ch*64 + (tid & 63);
  const int cg = tid >> 6;
  const short* vb = vc + (size_t)batch*NTOK*64;
  float acc[16];
  for (int i=0;i<16;i++) acc[i]=0.f;
  for (int d=0;d<64;d++) {
    float v = bf2f(vb[(size_t)d*4096 + n]);
    for (int ci=0;ci<16;ci++) acc[ci] += lA[(cg*16+ci)*64 + d] * v;
  }
  float* cb = chan + (size_t)batch*NTOK*64;
  for (int ci=0;ci<16;ci++) cb[(size_t)(cg*16+ci)*4096 + n] = acc[ci];
}

__global__ void zero_ws(float* p, int n4) {
  int i = blockIdx.x*blockDim.x + threadIdx.x;
  if (i < n4) ((f32x4*)p)[i] = (f32x4){0.f,0.f,0.f,0.f};
}

// ---- out = b*spat + a*chan + 2*x ----
__global__ __launch_bounds__(256) void fuse_out(const float* __restrict__ x,
    const float* __restrict__ spat, const float* __restrict__ chan,
    const float* __restrict__ pa, const float* __restrict__ pb,
    float* __restrict__ out) {
  int i = blockIdx.x*256 + threadIdx.x;
  float a = pa[0], b = pb[0];
  f32x4 xv = ((const f32x4*)x)[i];
  f32x4 sv = ((const f32x4*)spat)[i];
  f32x4 cv = ((const f32x4*)chan)[i];
  f32x4 r;
  for (int j=0;j<4;j++) r[j] = b*sv[j] + a*cv[j] + 2.f*xv[j];
  ((f32x4*)out)[i] = r;
}

extern "C" void kernel_launch(void* const* d_in, const int* in_sizes, int n_in,
                              void* d_out, int out_size, void* d_ws, size_t ws_size,
                              hipStream_t stream) {
  const float* x = (const float*)d_in[0];
  char* ws = (char*)d_ws;
  const size_t MB = 1048576;
  short* qs  = (short*)(ws + 0*MB);
  short* ks_ = (short*)(ws + 2*MB);
  short* vs  = (short*)(ws + 4*MB);
  short* qc  = (short*)(ws + 6*MB);
  short* kc  = (short*)(ws + 8*MB);
  short* vc  = (short*)(ws + 10*MB);
  float* spat = (float*)(ws + 12*MB);
  float* chan = (float*)(ws + 16*MB);
  float* G    = (float*)(ws + 20*MB);
  float* att  = (float*)(ws + 20*MB + 65536);

  ConvArgs ca;
  ca.x = x;
  for (int i=0;i<6;i++) {
    ca.w[i]    = (const float*)d_in[1+2*i];
    ca.bias[i] = (const float*)d_in[2+2*i];
  }
  ca.out[0]=qs; ca.out[1]=ks_; ca.out[2]=vs;
  ca.out[3]=qc; ca.out[4]=kc; ca.out[5]=vc;

  hipLaunchKernelGGL(zero_ws, dim3(16), dim3(256), 0, stream, G, 4096);
  hipLaunchKernelGGL(conv_qkv, dim3(256), dim3(256), 0, stream, ca);
  hipLaunchKernelGGL(attn_spatial, dim3(64,4), dim3(256), 0, stream, qs, ks_, vs, spat);
  hipLaunchKernelGGL(chan_qk, dim3(16,4), dim3(256), 0, stream, qc, kc, G);
  hipLaunchKernelGGL(chan_softmax, dim3(4), dim3(64), 0, stream, G, att);
  hipLaunchKernelGGL(chan_av, dim3(64,4), dim3(256), 0, stream, att, vc, chan);
  hipLaunchKernelGGL(fuse_out, dim3(1024), dim3(256), 0, stream,
                     x, spat, chan, (const float*)d_in[13], (const float*)d_in[14],
                     (float*)d_out);
}

// Round 2
// 219.013 us; speedup vs baseline: 1.2880x; 1.2880x over previous
//
#include <hip/hip_runtime.h>

#define NTOK 4096   // H*W
#define NB 4
#define PSTR 72     // padded LDS row stride (shorts): 144B = 4-bank offset per row

typedef short bf16x8 __attribute__((ext_vector_type(8)));
typedef float f32x4 __attribute__((ext_vector_type(4)));

__device__ __forceinline__ short f2bf(float f) {          // RNE
  union { float f; unsigned u; } v; v.f = f;
  unsigned r = v.u + 0x7fffu + ((v.u >> 16) & 1u);
  return (short)(r >> 16);
}
__device__ __forceinline__ short f2bf_t(float f) {        // truncate (P matrix only)
  union { float f; unsigned u; } v; v.f = f;
  return (short)(v.u >> 16);
}
__device__ __forceinline__ float bf2f(short s) {
  union { unsigned u; float f; } v; v.u = ((unsigned)(unsigned short)s) << 16;
  return v.f;
}

struct ConvArgs {
  const float* x;
  const float* w[6];
  const float* bias[6];
  short* out[6];   // out[2] is vs_t (channel-major); others token-major
};

// ---- fused 6-way 1x1 conv: y = x @ W + b -> bf16. out[2] written transposed ----
__global__ __launch_bounds__(256) void conv_qkv(ConvArgs args) {
  __shared__ __align__(16) short lWt[6][64*PSTR];   // W^T bf16
  __shared__ float lB[6*64];
  __shared__ __align__(16) short lT[64*PSTR];       // transpose buf for vs_t
  const int tid = threadIdx.x;
  const int wave = tid >> 6, lane = tid & 63;
  const int quad = lane >> 4, l16 = lane & 15;

  for (int wi = 0; wi < 6; wi++) {
    const f32x4* wsrc = (const f32x4*)args.w[wi];
    for (int u0 = 0; u0 < 4; u0++) {
      int u = u0 * 256 + tid;
      int c = u >> 4, d4 = u & 15;
      f32x4 v = wsrc[u];
      for (int j = 0; j < 4; j++)
        lWt[wi][(d4*4+j)*PSTR + c] = f2bf(v[j]);
    }
  }
  if (tid < 64)
    for (int wi = 0; wi < 6; wi++) lB[wi*64 + tid] = args.bias[wi][tid];

  int row = blockIdx.x * 64 + wave*16 + l16;
  const float* xr = args.x + (size_t)row*64 + quad*8;
  f32x4 x0 = *(const f32x4*)xr;
  f32x4 x1 = *(const f32x4*)(xr+4);
  f32x4 x2 = *(const f32x4*)(xr+32);
  f32x4 x3 = *(const f32x4*)(xr+36);
  bf16x8 a0, a1;
  for (int j=0;j<4;j++){ a0[j]=f2bf(x0[j]); a0[4+j]=f2bf(x1[j]); a1[j]=f2bf(x2[j]); a1[4+j]=f2bf(x3[j]); }
  __syncthreads();

  int orow_base = blockIdx.x*64 + wave*16 + quad*4;
  for (int wi=0; wi<6; wi++) {
    for (int dt=0; dt<4; dt++) {
      bf16x8 b0 = *(const bf16x8*)&lWt[wi][(dt*16+l16)*PSTR + quad*8];
      bf16x8 b1 = *(const bf16x8*)&lWt[wi][(dt*16+l16)*PSTR + 32 + quad*8];
      f32x4 acc = {0.f,0.f,0.f,0.f};
      acc = __builtin_amdgcn_mfma_f32_16x16x32_bf16(a0, b0, acc, 0,0,0);
      acc = __builtin_amdgcn_mfma_f32_16x16x32_bf16(a1, b1, acc, 0,0,0);
      float bias = lB[wi*64 + dt*16 + l16];
      if (wi != 2) {
        short* outp = args.out[wi];
        for (int r=0;r<4;r++)
          outp[(size_t)(orow_base + r)*64 + dt*16 + l16] = f2bf(acc[r] + bias);
      } else {
        for (int r=0;r<4;r++)
          lT[(dt*16+l16)*PSTR + wave*16 + quad*4 + r] = f2bf(acc[r] + bias);
      }
    }
  }
  __syncthreads();
  // coalesced store of the transposed V_s tile: vs_t[b][c][n0..n0+63]
  int b  = (blockIdx.x*64) >> 12;
  int n0 = (blockIdx.x*64) & 4095;
  for (int u0=0; u0<2; u0++) {
    int u = u0*256 + tid;
    int c = u >> 3, t8 = u & 7;
    *(bf16x8*)(args.out[2] + (size_t)(b*64+c)*4096 + n0 + t8*8) =
        *(const bf16x8*)&lT[c*PSTR + t8*8];
  }
}

// ---- flash spatial attention, in-block K-split ----
// block: 512 thr = 8 waves = 4 query strips x 2 key groups; grid (64 qtiles, 4 batch)
__global__ __launch_bounds__(512, 4) void attn_spatial(const short* __restrict__ qs,
    const short* __restrict__ ks, const short* __restrict__ vst,
    float* __restrict__ spat) {
  __shared__ __align__(16) short sStage[2][2][64*PSTR];  // [kg][0=K rows,1=V^T rows]
  __shared__ __align__(16) short sP[8][16*PSTR];
  __shared__ float sM[8][16];
  __shared__ float sL[8][16];
  const int tid = threadIdx.x;
  const int wave = tid>>6, lane = tid&63, quad = lane>>4, l16 = lane&15;
  const int kg = wave>>2, strip = wave&3;
  const int batch = blockIdx.y, qtile = blockIdx.x;
  const int ltid = tid & 255;

  // Q frag, pre-scaled by 1/sqrt(C) * log2(e) so softmax works in base-2 units
  const float SC = 0.125f * 1.44269504088896f;
  const short* qp = qs + ((size_t)(batch*NTOK + qtile*64 + strip*16 + l16))*64 + quad*8;
  bf16x8 qr0 = *(const bf16x8*)qp;
  bf16x8 qr1 = *(const bf16x8*)(qp + 32);
  bf16x8 qa0, qa1;
  for (int j=0;j<8;j++){ qa0[j]=f2bf(bf2f(qr0[j])*SC); qa1[j]=f2bf(bf2f(qr1[j])*SC); }

  f32x4 o[4];
  for (int ct=0;ct<4;ct++) o[ct] = (f32x4){0.f,0.f,0.f,0.f};
  float mi[4] = {-1e30f,-1e30f,-1e30f,-1e30f};
  float li[4] = {0.f,0.f,0.f,0.f};

  const short* kb  = ks  + (size_t)batch*NTOK*64;
  const short* vtb = vst + (size_t)batch*64*NTOK;
  short* myK = &sStage[kg][0][0];
  short* myV = &sStage[kg][1][0];

  for (int t=0; t<32; t++) {
    int k0 = kg*2048 + t*64;
    __syncthreads();
    for (int u0=0; u0<2; u0++) {
      int u = u0*256 + ltid;          // 512 units of 8 bf16 per buffer
      int r8 = u>>3, c8 = u&7;
      *(bf16x8*)&myK[r8*PSTR + c8*8] = *(const bf16x8*)(kb + (size_t)(k0+r8)*64 + c8*8);
      *(bf16x8*)&myV[r8*PSTR + c8*8] = *(const bf16x8*)(vtb + (size_t)r8*4096 + k0 + c8*8);
    }
    __syncthreads();

    f32x4 s[4];
    for (int nt=0;nt<4;nt++) {
      bf16x8 k0f = *(const bf16x8*)&myK[(nt*16+l16)*PSTR + quad*8];
      bf16x8 k1f = *(const bf16x8*)&myK[(nt*16+l16)*PSTR + 32 + quad*8];
      f32x4 z = {0.f,0.f,0.f,0.f};
      z = __builtin_amdgcn_mfma_f32_16x16x32_bf16(qa0, k0f, z, 0,0,0);
      z = __builtin_amdgcn_mfma_f32_16x16x32_bf16(qa1, k1f, z, 0,0,0);
      s[nt] = z;
    }
    float alpha[4];
    for (int r=0;r<4;r++) {
      float mx = fmaxf(fmaxf(s[0][r],s[1][r]), fmaxf(s[2][r],s[3][r]));
      mx = fmaxf(mx, __shfl_xor(mx, 1));
      mx = fmaxf(mx, __shfl_xor(mx, 2));
      mx = fmaxf(mx, __shfl_xor(mx, 4));
      mx = fmaxf(mx, __shfl_xor(mx, 8));
      float mnew = fmaxf(mi[r], mx);
      alpha[r] = __builtin_amdgcn_exp2f(mi[r]-mnew);
      float sum = 0.f;
      for (int nt=0;nt<4;nt++) {
        float p = __builtin_amdgcn_exp2f(s[nt][r]-mnew);
        s[nt][r] = p; sum += p;
      }
      sum += __shfl_xor(sum,1); sum += __shfl_xor(sum,2);
      sum += __shfl_xor(sum,4); sum += __shfl_xor(sum,8);
      li[r] = li[r]*alpha[r] + sum;
      mi[r] = mnew;
    }
    for (int ct=0;ct<4;ct++)
      for (int r=0;r<4;r++) o[ct][r] *= alpha[r];

    short* lPw = sP[wave];
    for (int nt=0;nt<4;nt++)
      for (int r=0;r<4;r++)
        lPw[(quad*4+r)*PSTR + nt*16 + l16] = f2bf_t(s[nt][r]);
    bf16x8 pa0 = *(const bf16x8*)&lPw[l16*PSTR + quad*8];
    bf16x8 pa1 = *(const bf16x8*)&lPw[l16*PSTR + 32 + quad*8];
    for (int ct=0;ct<4;ct++) {
      bf16x8 v0 = *(const bf16x8*)&myV[(ct*16+l16)*PSTR + quad*8];
      bf16x8 v1 = *(const bf16x8*)&myV[(ct*16+l16)*PSTR + 32 + quad*8];
      o[ct] = __builtin_amdgcn_mfma_f32_16x16x32_bf16(pa0, v0, o[ct], 0,0,0);
      o[ct] = __builtin_amdgcn_mfma_f32_16x16x32_bf16(pa1, v1, o[ct], 0,0,0);
    }
  }

  // ---- cross-kgroup combine (overlay sStage as f32 scratch) ----
  __syncthreads();
  float* lO = (float*)&sStage[0][0][0];     // 8 x (16x64) f32 = 32 KB <= 36.9 KB
  {
    int base = wave*1024;
    for (int ct=0;ct<4;ct++)
      for (int r=0;r<4;r++)
        lO[base + (quad*4+r)*64 + ct*16 + l16] = o[ct][r];
    if (l16 == 0)
      for (int r=0;r<4;r++) { sM[wave][quad*4+r] = mi[r]; sL[wave][quad*4+r] = li[r]; }
  }
  __syncthreads();
  for (int i=0;i<8;i++) {
    int e = i*512 + tid;                 // 4096 outputs: strip(4) x row(16) x col(64)
    int s_ = e>>10, row = (e>>6)&15, col = e&63;
    float m0 = sM[s_][row],   l0 = sL[s_][row];
    float m1 = sM[4+s_][row], l1 = sL[4+s_][row];
    float M = fmaxf(m0, m1);
    float w0 = __builtin_amdgcn_exp2f(m0-M), w1 = __builtin_amdgcn_exp2f(m1-M);
    float num = w0*lO[s_*1024 + row*64 + col] + w1*lO[(4+s_)*1024 + row*64 + col];
    float den = w0*l0 + w1*l1;
    spat[((size_t)batch*NTOK + qtile*64 + s_*16 + row)*64 + col] = num/den;
  }
}

// ---- channel attention: G = Qc Kc^T (K=4096) + softmax, fused. grid = 4 batches ----
__global__ void chan_qk_sm(const short* __restrict__ qc,
    const short* __restrict__ kc, float* __restrict__ att) {
  __shared__ float lRed[4][4096];
  const int tid = threadIdx.x;
  const int wave = tid>>6, lane = tid&63, quad = lane>>4, l16 = lane&15;
  const int batch = blockIdx.x;
  const short* qb = qc + (size_t)batch*NTOK*64;
  const short* kb = kc + (size_t)batch*NTOK*64;

  f32x4 acc[4][4];
  for (int mt=0;mt<4;mt++) for (int nt=0;nt<4;nt++) acc[mt][nt] = (f32x4){0.f,0.f,0.f,0.f};

  for (int ks_=0; ks_<16; ks_++) {
    int k0 = wave*1024 + ks_*64;
    for (int kh=0; kh<2; kh++) {
      bf16x8 aq[4], bk[4];
      for (int mt=0;mt<4;mt++)
        aq[mt] = *(const bf16x8*)(qb + (size_t)(mt*16+l16)*4096 + k0 + kh*32 + quad*8);
      for (int nt=0;nt<4;nt++)
        bk[nt] = *(const bf16x8*)(kb + (size_t)(nt*16+l16)*4096 + k0 + kh*32 + quad*8);
      for (int mt=0;mt<4;mt++)
        for (int nt=0;nt<4;nt++)
          acc[mt][nt] = __builtin_amdgcn_mfma_f32_16x16x32_bf16(aq[mt], bk[nt], acc[mt][nt], 0,0,0);
    }
  }
  for (int mt=0;mt<4;mt++)
    for (int nt=0;nt<4;nt++)
      for (int r=0;r<4;r++)
        lRed[wave][(mt*16+quad*4+r)*64 + nt*16+l16] = acc[mt][nt][r];
  __syncthreads();
  for (int i=tid;i<4096;i+=256)
    lRed[0][i] += lRed[1][i] + lRed[2][i] + lRed[3][i];
  __syncthreads();
  if (tid < 64) {
    const float* g = &lRed[0][tid*64];
    float mx = -1e30f;
    for (int d=0;d<64;d++) mx = fmaxf(mx, g[d]*0.125f);
    float sum = 0.f;
    for (int d=0;d<64;d++) sum += __builtin_amdgcn_exp2f((g[d]*0.125f - mx)*1.44269504f);
    float inv = 1.f/sum;
    float* o = att + batch*4096 + tid*64;
    for (int d=0;d<64;d++)
      o[d] = __builtin_amdgcn_exp2f((g[d]*0.125f - mx)*1.44269504f)*inv;
  }
}

// ---- chan[c][n] = sum_d att[c][d] * Vc[d][n] ----
__global__ __launch_bounds__(256) void chan_av(const float* __restrict__ att,
    const short* __restrict__ vc, float* __restrict__ chan) {
  __shared__ float lA[4096];
  const int tid = threadIdx.x;
  const int batch = blockIdx.y, ch = blockIdx.x;
  for (int i=tid;i<4096;i+=256) lA[i] = att[batch*4096+i];
  __syncthreads();
  const int n = ch*64 + (tid & 63);
  const int cg = tid >> 6;
  const short* vb = vc + (size_t)batch*NTOK*64;
  float acc[16];
  for (int i=0;i<16;i++) acc[i]=0.f;
  for (int d=0;d<64;d++) {
    float v = bf2f(vb[(size_t)d*4096 + n]);
    for (int ci=0;ci<16;ci++) acc[ci] += lA[(cg*16+ci)*64 + d] * v;
  }
  float* cb = chan + (size_t)batch*NTOK*64;
  for (int ci=0;ci<16;ci++) cb[(size_t)(cg*16+ci)*4096 + n] = acc[ci];
}

// ---- out = b*spat + a*chan + 2*x ----
__global__ __launch_bounds__(256) void fuse_out(const float* __restrict__ x,
    const float* __restrict__ spat, const float* __restrict__ chan,
    const float* __restrict__ pa, const float* __restrict__ pb,
    float* __restrict__ out) {
  int i = blockIdx.x*256 + threadIdx.x;
  float a = pa[0], b = pb[0];
  f32x4 xv = ((const f32x4*)x)[i];
  f32x4 sv = ((const f32x4*)spat)[i];
  f32x4 cv = ((const f32x4*)chan)[i];
  f32x4 r;
  for (int j=0;j<4;j++) r[j] = b*sv[j] + a*cv[j] + 2.f*xv[j];
  ((f32x4*)out)[i] = r;
}

extern "C" void kernel_launch(void* const* d_in, const int* in_sizes, int n_in,
                              void* d_out, int out_size, void* d_ws, size_t ws_size,
                              hipStream_t stream) {
  const float* x = (const float*)d_in[0];
  char* ws = (char*)d_ws;
  const size_t MB = 1048576;
  short* qs   = (short*)(ws + 0*MB);
  short* ks_  = (short*)(ws + 2*MB);
  short* vst  = (short*)(ws + 4*MB);   // channel-major spatial V
  short* qc   = (short*)(ws + 6*MB);
  short* kc   = (short*)(ws + 8*MB);
  short* vc   = (short*)(ws + 10*MB);
  float* spat = (float*)(ws + 12*MB);
  float* chan = (float*)(ws + 16*MB);
  float* att  = (float*)(ws + 20*MB);

  ConvArgs ca;
  ca.x = x;
  for (int i=0;i<6;i++) {
    ca.w[i]    = (const float*)d_in[1+2*i];
    ca.bias[i] = (const float*)d_in[2+2*i];
  }
  ca.out[0]=qs; ca.out[1]=ks_; ca.out[2]=vst;
  ca.out[3]=qc; ca.out[4]=kc; ca.out[5]=vc;

  hipLaunchKernelGGL(conv_qkv, dim3(256), dim3(256), 0, stream, ca);
  hipLaunchKernelGGL(attn_spatial, dim3(64,4), dim3(512), 0, stream, qs, ks_, vst, spat);
  hipLaunchKernelGGL(chan_qk_sm, dim3(4), dim3(256), 0, stream, qc, kc, att);
  hipLaunchKernelGGL(chan_av, dim3(64,4), dim3(256), 0, stream, att, vc, chan);
  hipLaunchKernelGGL(fuse_out, dim3(1024), dim3(256), 0, stream,
                     x, spat, chan, (const float*)d_in[13], (const float*)d_in[14],
                     (float*)d_out);
}